// Round 11
// baseline (238.688 us; speedup 1.0000x reference)
//
#include <hip/hip_runtime.h>
#include <hip/hip_bf16.h>

typedef __attribute__((ext_vector_type(8))) short bf16x8;
typedef __attribute__((ext_vector_type(8))) ushort ushort8;
typedef __attribute__((ext_vector_type(4))) float f32x4;

#define T_TOK 4096
#define HDIM  1024
#define IDIM  768
#define NEXP  8
#define TOPK  2
#define NSLOT (T_TOK * TOPK)   // 8192 token-slots

#define BM  128
#define BN  128
#define BKS 32                 // K elements per LDS tile (1 MFMA k-step)

#define NX8 (T_TOK * HDIM / 8) // 524288 ushort8 items of x

__device__ __forceinline__ ushort f2bf(float f) {
  union { __hip_bfloat16 h; ushort u; } cv;
  cv.h = __float2bfloat16(f);
  return cv.u;
}
__device__ __forceinline__ float bf2f(ushort u) {
  union { float f; uint v; } cv; cv.v = ((uint)u) << 16; return cv.f;
}

__device__ __forceinline__ void gload_lds16(const ushort* g, ushort* l) {
  __builtin_amdgcn_global_load_lds(
      (const __attribute__((address_space(1))) void*)g,
      (__attribute__((address_space(3))) void*)l, 16, 0, 0);
}

__device__ __forceinline__ ushort8 pack_bf16(float4 a, float4 b) {
  ushort8 o;
  o[0] = f2bf(a.x); o[1] = f2bf(a.y); o[2] = f2bf(a.z); o[3] = f2bf(a.w);
  o[4] = f2bf(b.x); o[5] = f2bf(b.y); o[6] = f2bf(b.z); o[7] = f2bf(b.w);
  return o;
}

// ---- fused: route (first 32 blocks) + fp32->bf16 conversion of x ONLY ----
__global__ void cvt_x_route(const float* __restrict__ hs, ushort* __restrict__ xb,
                            const int* __restrict__ sel, int* __restrict__ counts,
                            int* __restrict__ toklist) {
  int bid = blockIdx.x;
  if (bid < 32) {                       // routing: 32*256 = 8192 slots
    int slot = bid * 256 + threadIdx.x;
    int e = sel[slot];
    int idx = atomicAdd(&counts[e], 1);
    toklist[e * NSLOT + idx] = slot;
    return;
  }
  int i = (bid - 32) * 256 + threadIdx.x;   // ushort8 item index
  const float4* s4 = reinterpret_cast<const float4*>(hs) + 2 * (size_t)i;
  float4 v0 = s4[0];
  float4 v1 = s4[1];
  reinterpret_cast<ushort8*>(xb)[i] = pack_bf16(v0, v1);
}

// swizzle: read (row r, chunk c) at stored chunk c ^ ((r>>1)&3);
// stage lane l writes LDS linearly (lane*16B) and fetches global chunk (l&3)^((l>>3)&3)

// ---- GEMM1: act[slot] = silu(x @ Wg^T) * (x @ Wu^T); B = fp32 weights,
//      reg-staged with in-flight fp32->bf16 convert (T14 split) ----
__launch_bounds__(256, 2)
__global__ void gemm_gateup(const ushort* __restrict__ xb,
                            const float* __restrict__ gw,
                            const float* __restrict__ uw,
                            const int* __restrict__ counts,
                            const int* __restrict__ toklist,
                            ushort* __restrict__ act) {
  const int b = blockIdx.x;
  const int e = b & 7;                    // expert == XCD (L2 locality)
  const int r = b >> 3;
  const int nt = r % 6, mt = r / 6;       // mt slowest -> active blocks front-loaded
  const int cnt = counts[e];
  const int m0 = mt * BM;
  if (m0 >= cnt) return;
  const int n0 = nt * BN;

  __shared__ __align__(16) ushort As[2][BM * BKS];    // 2 x 8 KB
  __shared__ __align__(16) ushort Bgs[2][BM * BKS];   // 2 x 8 KB
  __shared__ __align__(16) ushort Bus[2][BM * BKS];   // 2 x 8 KB  = 48 KB

  const int tid = threadIdx.x;
  const int wave = tid >> 6, lane = tid & 63;
  const int wm = wave >> 1, wn = wave & 1;            // 2x2 waves, 64x64 out each
  const int lrow = lane & 15, lk16 = lane >> 4;
  const int rl = lane >> 2;                           // row within 16-row segment
  const int gck = ((lane & 3) ^ ((lane >> 3) & 3)) << 3;  // elem offset of src chunk

  const int ent0 = m0 + wave * 16 + rl;
  const int ent1 = ent0 + 64;
  const int arow0 = (ent0 < cnt) ? (toklist[e * NSLOT + ent0] >> 1) : 0;
  const int arow1 = (ent1 < cnt) ? (toklist[e * NSLOT + ent1] >> 1) : 0;
  const int brow0 = wave * 16 + rl;                   // 0..63
  const int brow1 = brow0 + 64;                       // 64..127

  const ushort* aP0 = xb + (size_t)arow0 * HDIM + gck;
  const ushort* aP1 = xb + (size_t)arow1 * HDIM + gck;
  const float* gP0 = gw + (size_t)e * IDIM * HDIM + (size_t)(n0 + brow0) * HDIM + gck;
  const float* gP1 = gw + (size_t)e * IDIM * HDIM + (size_t)(n0 + brow1) * HDIM + gck;
  const float* uP0 = uw + (size_t)e * IDIM * HDIM + (size_t)(n0 + brow0) * HDIM + gck;
  const float* uP1 = uw + (size_t)e * IDIM * HDIM + (size_t)(n0 + brow1) * HDIM + gck;

  f32x4 accg[4][4], accu[4][4];
  const f32x4 fzero = {0.f, 0.f, 0.f, 0.f};
  #pragma unroll
  for (int a = 0; a < 4; ++a)
    #pragma unroll
    for (int c = 0; c < 4; ++c) { accg[a][c] = fzero; accu[a][c] = fzero; }

  // in-flight fp32 B values (one set; consumed before next issue)
  float4 vgl0, vgl1, vgh0, vgh1, vul0, vul1, vuh0, vuh1;

  auto issue = [&](int buf, int k0) {               // A -> LDS direct; B -> regs
    gload_lds16(aP0 + k0, &As[buf][wave * 512]);
    gload_lds16(aP1 + k0, &As[buf][(wave + 4) * 512]);
    const float4* g0 = reinterpret_cast<const float4*>(gP0 + k0);
    const float4* g1 = reinterpret_cast<const float4*>(gP1 + k0);
    const float4* u0 = reinterpret_cast<const float4*>(uP0 + k0);
    const float4* u1 = reinterpret_cast<const float4*>(uP1 + k0);
    vgl0 = g0[0]; vgl1 = g0[1];
    vgh0 = g1[0]; vgh1 = g1[1];
    vul0 = u0[0]; vul1 = u0[1];
    vuh0 = u1[0]; vuh1 = u1[1];
  };
  auto commit = [&](int buf) {                      // cvt + LDS write (linear dest)
    *reinterpret_cast<ushort8*>(&Bgs[buf][wave * 512 + lane * 8]) = pack_bf16(vgl0, vgl1);
    *reinterpret_cast<ushort8*>(&Bgs[buf][(wave + 4) * 512 + lane * 8]) = pack_bf16(vgh0, vgh1);
    *reinterpret_cast<ushort8*>(&Bus[buf][wave * 512 + lane * 8]) = pack_bf16(vul0, vul1);
    *reinterpret_cast<ushort8*>(&Bus[buf][(wave + 4) * 512 + lane * 8]) = pack_bf16(vuh0, vuh1);
  };

  const int swzc = ((lk16 ^ ((lrow >> 1) & 3)) << 3);
  auto compute = [&](int buf) {
    bf16x8 aF[4], bgF[4], buF[4];
    #pragma unroll
    for (int mi = 0; mi < 4; ++mi) {
      int rr = wm * 64 + mi * 16 + lrow;
      aF[mi] = *reinterpret_cast<const bf16x8*>(&As[buf][rr * 32 + swzc]);
    }
    #pragma unroll
    for (int ni = 0; ni < 4; ++ni) {
      int rr = wn * 64 + ni * 16 + lrow;
      bgF[ni] = *reinterpret_cast<const bf16x8*>(&Bgs[buf][rr * 32 + swzc]);
      buF[ni] = *reinterpret_cast<const bf16x8*>(&Bus[buf][rr * 32 + swzc]);
    }
    #pragma unroll
    for (int mi = 0; mi < 4; ++mi)
      #pragma unroll
      for (int ni = 0; ni < 4; ++ni) {
        accg[mi][ni] = __builtin_amdgcn_mfma_f32_16x16x32_bf16(aF[mi], bgF[ni], accg[mi][ni], 0, 0, 0);
        accu[mi][ni] = __builtin_amdgcn_mfma_f32_16x16x32_bf16(aF[mi], buF[ni], accu[mi][ni], 0, 0, 0);
      }
  };

  const int NT = HDIM / BKS;                        // 32 (even)
  issue(0, 0);
  commit(0);
  __syncthreads();
  #pragma unroll 1
  for (int t = 0; t < NT; t += 2) {
    if (t + 1 < NT) issue(1, (t + 1) * BKS);
    compute(0);
    if (t + 1 < NT) commit(1);
    __syncthreads();
    if (t + 2 < NT) issue(0, (t + 2) * BKS);
    compute(1);
    if (t + 2 < NT) commit(0);
    __syncthreads();
  }

  // epilogue: y = silu(g)*u -> bf16 act[slot][col]; C/D: col=lane&15, row=(lane>>4)*4+j
  const int lcol = lane & 15;
  const int lrb = (lane >> 4) * 4;
  #pragma unroll
  for (int mi = 0; mi < 4; ++mi)
    #pragma unroll
    for (int j = 0; j < 4; ++j) {
      int row = wm * 64 + mi * 16 + lrb + j;
      int entry = m0 + row;
      if (entry >= cnt) continue;
      int slot = toklist[e * NSLOT + entry];
      #pragma unroll
      for (int ni = 0; ni < 4; ++ni) {
        int col = n0 + wn * 64 + ni * 16 + lcol;
        float g = accg[mi][ni][j];
        float u = accu[mi][ni][j];
        float y = (g / (1.0f + __expf(-g))) * u;
        act[(size_t)slot * IDIM + col] = f2bf(y);
      }
    }
}

// ---- GEMM2: yact[slot] = act[slot] @ Wd^T; B = fp32 down-weights reg-staged ----
__launch_bounds__(256, 3)
__global__ void gemm_down(const ushort* __restrict__ act,
                          const float* __restrict__ dw,
                          const int* __restrict__ counts,
                          const int* __restrict__ toklist,
                          ushort* __restrict__ yact) {
  const int b = blockIdx.x;
  const int e = b & 7;
  const int r = b >> 3;
  const int nt = r & 7, mt = r >> 3;      // HDIM/BN = 8
  const int cnt = counts[e];
  const int m0 = mt * BM;
  if (m0 >= cnt) return;
  const int n0 = nt * BN;

  __shared__ __align__(16) ushort As[2][BM * BKS];    // 2 x 8 KB
  __shared__ __align__(16) ushort Bs[2][BM * BKS];    // 2 x 8 KB = 32 KB

  const int tid = threadIdx.x;
  const int wave = tid >> 6, lane = tid & 63;
  const int wm = wave >> 1, wn = wave & 1;
  const int lrow = lane & 15, lk16 = lane >> 4;
  const int rl = lane >> 2;
  const int gck = ((lane & 3) ^ ((lane >> 3) & 3)) << 3;

  const int ent0 = m0 + wave * 16 + rl;
  const int ent1 = ent0 + 64;
  const int arow0 = (ent0 < cnt) ? toklist[e * NSLOT + ent0] : 0;  // slot id
  const int arow1 = (ent1 < cnt) ? toklist[e * NSLOT + ent1] : 0;
  const int brow0 = wave * 16 + rl;
  const int brow1 = brow0 + 64;

  const ushort* aP0 = act + (size_t)arow0 * IDIM + gck;
  const ushort* aP1 = act + (size_t)arow1 * IDIM + gck;
  const float* dP0 = dw + (size_t)e * HDIM * IDIM + (size_t)(n0 + brow0) * IDIM + gck;
  const float* dP1 = dw + (size_t)e * HDIM * IDIM + (size_t)(n0 + brow1) * IDIM + gck;

  f32x4 acc[4][4];
  const f32x4 fzero = {0.f, 0.f, 0.f, 0.f};
  #pragma unroll
  for (int a = 0; a < 4; ++a)
    #pragma unroll
    for (int c = 0; c < 4; ++c) acc[a][c] = fzero;

  float4 vdl0, vdl1, vdh0, vdh1;

  auto issue = [&](int buf, int k0) {
    gload_lds16(aP0 + k0, &As[buf][wave * 512]);
    gload_lds16(aP1 + k0, &As[buf][(wave + 4) * 512]);
    const float4* d0 = reinterpret_cast<const float4*>(dP0 + k0);
    const float4* d1 = reinterpret_cast<const float4*>(dP1 + k0);
    vdl0 = d0[0]; vdl1 = d0[1];
    vdh0 = d1[0]; vdh1 = d1[1];
  };
  auto commit = [&](int buf) {
    *reinterpret_cast<ushort8*>(&Bs[buf][wave * 512 + lane * 8]) = pack_bf16(vdl0, vdl1);
    *reinterpret_cast<ushort8*>(&Bs[buf][(wave + 4) * 512 + lane * 8]) = pack_bf16(vdh0, vdh1);
  };

  const int swzc = ((lk16 ^ ((lrow >> 1) & 3)) << 3);
  auto compute = [&](int buf) {
    bf16x8 aF[4], bF[4];
    #pragma unroll
    for (int mi = 0; mi < 4; ++mi) {
      int rr = wm * 64 + mi * 16 + lrow;
      aF[mi] = *reinterpret_cast<const bf16x8*>(&As[buf][rr * 32 + swzc]);
    }
    #pragma unroll
    for (int ni = 0; ni < 4; ++ni) {
      int rr = wn * 64 + ni * 16 + lrow;
      bF[ni] = *reinterpret_cast<const bf16x8*>(&Bs[buf][rr * 32 + swzc]);
    }
    #pragma unroll
    for (int mi = 0; mi < 4; ++mi)
      #pragma unroll
      for (int ni = 0; ni < 4; ++ni)
        acc[mi][ni] = __builtin_amdgcn_mfma_f32_16x16x32_bf16(aF[mi], bF[ni], acc[mi][ni], 0, 0, 0);
  };

  const int NT = IDIM / BKS;                        // 24 (even)
  issue(0, 0);
  commit(0);
  __syncthreads();
  #pragma unroll 1
  for (int t = 0; t < NT; t += 2) {
    if (t + 1 < NT) issue(1, (t + 1) * BKS);
    compute(0);
    if (t + 1 < NT) commit(1);
    __syncthreads();
    if (t + 2 < NT) issue(0, (t + 2) * BKS);
    compute(1);
    if (t + 2 < NT) commit(0);
    __syncthreads();
  }

  const int lcol = lane & 15;
  const int lrb = (lane >> 4) * 4;
  #pragma unroll
  for (int mi = 0; mi < 4; ++mi)
    #pragma unroll
    for (int j = 0; j < 4; ++j) {
      int row = wm * 64 + mi * 16 + lrb + j;
      int entry = m0 + row;
      if (entry >= cnt) continue;
      int slot = toklist[e * NSLOT + entry];
      #pragma unroll
      for (int ni = 0; ni < 4; ++ni) {
        int col = n0 + wn * 64 + ni * 16 + lcol;
        yact[(size_t)slot * HDIM + col] = f2bf(acc[mi][ni][j]);
      }
    }
}

// ---- combine: out[t] = rw[2t]*yact[2t] + rw[2t+1]*yact[2t+1] ----
__global__ void combine_kernel(const ushort* __restrict__ yact, const float* __restrict__ rw,
                               float* __restrict__ out) {
  int i = blockIdx.x * blockDim.x + threadIdx.x;
  int t = i >> 7;
  int h0 = (i & 127) << 3;
  const bf16x8 y0 = *reinterpret_cast<const bf16x8*>(yact + (size_t)(2 * t) * HDIM + h0);
  const bf16x8 y1 = *reinterpret_cast<const bf16x8*>(yact + (size_t)(2 * t + 1) * HDIM + h0);
  float w0 = rw[2 * t], w1 = rw[2 * t + 1];
  float o[8];
  #pragma unroll
  for (int j = 0; j < 8; ++j)
    o[j] = w0 * bf2f((ushort)y0[j]) + w1 * bf2f((ushort)y1[j]);
  float4* op = reinterpret_cast<float4*>(out + (size_t)t * HDIM + h0);
  op[0] = make_float4(o[0], o[1], o[2], o[3]);
  op[1] = make_float4(o[4], o[5], o[6], o[7]);
}

extern "C" void kernel_launch(void* const* d_in, const int* in_sizes, int n_in,
                              void* d_out, int out_size, void* d_ws, size_t ws_size,
                              hipStream_t stream) {
  const float* hs = (const float*)d_in[0];
  const float* rw = (const float*)d_in[1];
  const int*   se = (const int*)d_in[2];
  const float* gw = (const float*)d_in[3];
  const float* uw = (const float*)d_in[4];
  const float* dw = (const float*)d_in[5];
  float* out = (float*)d_out;

  // workspace layout (bytes) — weights no longer converted, much smaller
  char* base = (char*)d_ws;
  ushort* xb      = (ushort*)(base + 0);           //  8,388,608   x bf16
  ushort* act     = (ushort*)(base + 8388608);     // 12,582,912   [slot][IDIM] bf16
  ushort* yact    = (ushort*)(base + 20971520);    // 16,777,216   [slot][HDIM] bf16
  int*    toklist = (int*)(base + 37748736);       //    262,144
  int*    counts  = (int*)(base + 38010880);       //         32

  hipMemsetAsync(counts, 0, 256, stream);

  cvt_x_route<<<32 + NX8 / 256, 256, 0, stream>>>(hs, xb, se, counts, toklist);
  gemm_gateup<<<8 * 6 * (NSLOT / BM), 256, 0, stream>>>(xb, gw, uw, counts, toklist, act);
  gemm_down<<<8 * 8 * (NSLOT / BM), 256, 0, stream>>>(act, dw, counts, toklist, yact);
  combine_kernel<<<T_TOK * HDIM / 8 / 256, 256, 0, stream>>>(yact, rw, out);
}